// Round 6
// baseline (333.073 us; speedup 1.0000x reference)
//
#include <hip/hip_runtime.h>
#include <stdint.h>

#define NB 64
#define NT 512
#define NH 768
#define NS 128
#define NM (NB*NS)   // 8192 rows

typedef _Float16 half8 __attribute__((ext_vector_type(8)));
typedef _Float16 half4 __attribute__((ext_vector_type(4)));
typedef __attribute__((ext_vector_type(4))) float f32x4;

__device__ __forceinline__ float gelu_exact(float x) {
  return 0.5f * x * (1.0f + erff(x * 0.70710678118654752440f));
}

// async global->LDS, 16B per lane; LDS dest is wave-uniform base (HW adds lane*16)
__device__ __forceinline__ void gll16(const void* g, void* l) {
  __builtin_amdgcn_global_load_lds(
      (__attribute__((address_space(1))) unsigned int*)g,
      (__attribute__((address_space(3))) unsigned int*)l,
      16, 0, 0);
}

// ---------------------------------------------------------------------------
// Weight prep: w[k][n] f32 -> W[w][n][k] f16, PLAIN row-major (no swizzle:
// W is consumed straight from global as MFMA B-fragments, never staged in LDS)
// ---------------------------------------------------------------------------
__global__ void prep_w_kernel(const float* __restrict__ w1, const float* __restrict__ w2,
                              _Float16* __restrict__ W) {
  int id = blockIdx.x * 256 + threadIdx.x;   // 2*96*768 total
  int n  = id % NH;
  int t  = id / NH;
  int kc = t % 96;
  int w  = t / 96;
  const float* src = w ? w2 : w1;
  int k0 = kc * 8;
  half8 h;
#pragma unroll
  for (int i = 0; i < 8; ++i)
    h[i] = (_Float16)src[(size_t)(k0 + i) * NH + n];   // coalesced across n
  *(half8*)&W[(size_t)w * NH * NH + (size_t)n * NH + k0] = h;
}

// ---------------------------------------------------------------------------
// Fused pool: segment-mean + f16 hi/lo split, PLAIN row-major store. No atomics.
// grid (12 col-chunks, 64 batches), 256 threads = 16 seg-groups x 16 f32x4-cols.
// ---------------------------------------------------------------------------
__global__ __launch_bounds__(256)
void pool_kernel(const float* __restrict__ hidden, const int* __restrict__ sid,
                 _Float16* __restrict__ Ahi, _Float16* __restrict__ Alo) {
  __shared__ int   s_sid[NT];
  __shared__ short s_e0[NS + 1];
  const int b = blockIdx.y, cc = blockIdx.x;
  const int tid = threadIdx.x;
  for (int t = tid; t < NT; t += 256) s_sid[t] = sid[b * NT + t];
  __syncthreads();
  for (int t = tid; t < NT; t += 256) {
    const int cur  = s_sid[t];
    const int prev = t ? s_sid[t - 1] : -1;
    for (int s = prev + 1; s <= cur; ++s) s_e0[s] = (short)t;   // each s written once
    if (t == NT - 1)
      for (int s = cur + 1; s <= NS; ++s) s_e0[s] = (short)NT;
  }
  __syncthreads();

  const int c4  = tid & 15;           // 16 f32x4 column groups -> 64 cols
  const int sg  = tid >> 4;           // 16 segment groups
  const int col = cc * 64 + c4 * 4;
  const float* hb = hidden + (size_t)b * NT * NH;

  for (int s = sg; s < NS; s += 16) { // 8 segments per thread, strided for balance
    const int e0 = s_e0[s], e1 = s_e0[s + 1];
    f32x4 acc = {0.f, 0.f, 0.f, 0.f};
    for (int t = e0; t < e1; ++t)
      acc += *(const f32x4*)(hb + (size_t)t * NH + col);
    const float inv = 1.0f / (float)((e1 > e0) ? (e1 - e0) : 1);
    const int m = b * NS + s;
    half4 h, l;
#pragma unroll
    for (int j = 0; j < 4; ++j) {
      float x = acc[j] * inv;
      h[j] = (_Float16)x;
      l[j] = (_Float16)(x - (float)h[j]);
    }
    const size_t off = (size_t)m * NH + col;   // plain row-major
    *(half4*)&Ahi[off] = h;
    *(half4*)&Alo[off] = l;
  }
}

__global__ void finish_kernel(const float* __restrict__ part, const float* __restrict__ b3,
                              float* __restrict__ out) {
  int i = blockIdx.x * 256 + threadIdx.x;
  float s = b3[0];
#pragma unroll
  for (int j = 0; j < 12; ++j) s += part[(size_t)j * NM + i];
  out[i] = 1.0f / (1.0f + expf(-s));
}

// ---------------------------------------------------------------------------
// f16x2 GEMM, 32x128 tile, BK=128, 4 waves (2 row-halves x 2 col-halves).
// A (hi/lo) staged in LDS via gll16 with SOURCE-address XOR swizzle
// (LDS dest linear; read applies the same XOR -> bank-conflict-free, m173).
// W is NOT staged: B-fragments loaded global->VGPR per (kk,nf) with the exact
// MFMA lane layout (row = col0+wc*64+nf*16+lr, k = kb+kk*32+lk*8). W panel is
// L2-resident under the XCD-chunked grid.
// Grid 256 mb x 6 nb = 1536 blocks.
// EPI==0: C = gelu(A@W^T + bias) -> plain f16 hi/lo store
// EPI==1: per-row dot(gelu(..), w3) -> part[(nb*2+wc)][row]
// ---------------------------------------------------------------------------
template <int EPI>
__global__ __launch_bounds__(256, 4)
void gemm_kernel(const _Float16* __restrict__ Ahi, const _Float16* __restrict__ Alo,
                 const _Float16* __restrict__ Wg, const float* __restrict__ bias,
                 _Float16* __restrict__ Chi, _Float16* __restrict__ Clo,
                 const float* __restrict__ w3, float* __restrict__ part) {
  __shared__ _Float16 lds[8192];   // Ahi [0,4096) | Alo [4096,8192) elems; 16 KB

  const int tid  = threadIdx.x;
  const int lane = tid & 63;
  const int wave = tid >> 6;
  const int wr = wave >> 1, wc = wave & 1;

  // XCD-chunked bijective swizzle: 1536 = 8 XCDs * 192; the 6 nb-siblings of
  // an A-panel stay on one XCD -> W layer (1.2 MB) + A-slice L2-resident.
  const int bid = blockIdx.x;
  const int idp = (bid & 7) * 192 + (bid >> 3);
  const int mb = idp / 6, nb = idp % 6;
  const int row0 = mb * 32, col0 = nb * 128;

  const int lr  = lane & 15;
  const int lk4 = lane >> 4;                 // 0..3
  const int lcol = lr * 8;                   // staging col, 8 elems = 16B

  // per-nf W row base (row layout fixed for whole K loop)
  const _Float16* wrow[4];
#pragma unroll
  for (int nf = 0; nf < 4; ++nf)
    wrow[nf] = Wg + (size_t)(col0 + wc * 64 + nf * 16 + lr) * NH + lk4 * 8;

  f32x4 acc[4] = {};

  for (int kt = 0; kt < NH / 128; ++kt) {
    const int kb = kt * 128;

    // W fragments for all 4 kk of this K-step: 16 x global_load_dwordx4
    half8 bw[4][4];
#pragma unroll
    for (int kk = 0; kk < 4; ++kk)
#pragma unroll
      for (int nf = 0; nf < 4; ++nf)
        bw[kk][nf] = *(const half8*)(wrow[nf] + kb + kk * 32);

    // stage A hi/lo: 8 chunks x 1KB each precision; 4 gll16 per wave
#pragma unroll
    for (int i = 0; i < 2; ++i) {
      const int chunk = i * 4 + wave;        // 0..7
      const int r = chunk * 4 + lk4;         // 0..31
      const size_t src = (size_t)(row0 + r) * NH + kb + (lcol ^ ((r & 7) << 3));
      gll16(Ahi + src, &lds[chunk * 512]);
      gll16(Alo + src, &lds[4096 + chunk * 512]);
    }
    __syncthreads();

#pragma unroll
    for (int kk = 0; kk < 4; ++kk) {
      const int ar = wr * 16 + lr;           // A row 0..31
      const int ad = ar * 128 + ((kk * 32 + lk4 * 8) ^ ((ar & 7) << 3));
      half8 ah = *(const half8*)&lds[ad];
      half8 al = *(const half8*)&lds[4096 + ad];
#pragma unroll
      for (int nf = 0; nf < 4; ++nf) {
        acc[nf] = __builtin_amdgcn_mfma_f32_16x16x32_f16(ah, bw[kk][nf], acc[nf], 0, 0, 0);
        acc[nf] = __builtin_amdgcn_mfma_f32_16x16x32_f16(al, bw[kk][nf], acc[nf], 0, 0, 0);
      }
    }
    __syncthreads();
  }

  // epilogue. C/D layout: col = lane&15, row = (lane>>4)*4 + reg  [m89-verified]
  if (EPI == 0) {
#pragma unroll
    for (int nf = 0; nf < 4; ++nf) {
      const int col = col0 + wc * 64 + nf * 16 + lr;
      const float bv = bias[col];
#pragma unroll
      for (int r = 0; r < 4; ++r) {
        const int rowm = row0 + wr * 16 + lk4 * 4 + r;
        float g = gelu_exact(acc[nf][r] + bv);
        _Float16 h = (_Float16)g;
        _Float16 l = (_Float16)(g - (float)h);
        const size_t off = (size_t)rowm * NH + col;   // plain row-major
        Chi[off] = h;
        Clo[off] = l;
      }
    }
  } else {
    float bv[4], wv[4];
#pragma unroll
    for (int nf = 0; nf < 4; ++nf) {
      const int col = col0 + wc * 64 + nf * 16 + lr;
      bv[nf] = bias[col];
      wv[nf] = w3[col];
    }
#pragma unroll
    for (int r = 0; r < 4; ++r) {
      float p = 0.f;
#pragma unroll
      for (int nf = 0; nf < 4; ++nf)
        p += gelu_exact(acc[nf][r] + bv[nf]) * wv[nf];
      p += __shfl_xor(p, 1, 16);
      p += __shfl_xor(p, 2, 16);
      p += __shfl_xor(p, 4, 16);
      p += __shfl_xor(p, 8, 16);
      if (lr == 0) {
        const int rowm = row0 + wr * 16 + lk4 * 4 + r;
        part[((size_t)(nb * 2 + wc)) * NM + rowm] = p;   // distinct slot per column-half
      }
    }
  }
}

// ---------------------------------------------------------------------------
extern "C" void kernel_launch(void* const* d_in, const int* in_sizes, int n_in,
                              void* d_out, int out_size, void* d_ws, size_t ws_size,
                              hipStream_t stream) {
  (void)in_sizes; (void)n_in; (void)out_size; (void)ws_size;
  const float* hidden = (const float*)d_in[0];
  const int*   sid    = (const int*)d_in[1];
  const float* w1     = (const float*)d_in[2];
  const float* b1     = (const float*)d_in[3];
  const float* w2     = (const float*)d_in[4];
  const float* b2     = (const float*)d_in[5];
  const float* w3     = (const float*)d_in[6];
  const float* b3     = (const float*)d_in[7];
  float* out = (float*)d_out;

  char* p = (char*)d_ws;
  const size_t actE = (size_t)NM * NH;
  _Float16* Ahi  = (_Float16*)p; p += actE * 2;
  _Float16* Alo  = (_Float16*)p; p += actE * 2;
  _Float16* X1hi = (_Float16*)p; p += actE * 2;
  _Float16* X1lo = (_Float16*)p; p += actE * 2;
  _Float16* W    = (_Float16*)p; p += (size_t)2 * NH * NH * 2;
  float*    part = (float*)p;    p += (size_t)12 * NM * 4;

  prep_w_kernel<<<2 * 96 * NH / 256, 256, 0, stream>>>(w1, w2, W);
  pool_kernel<<<dim3(12, NB), 256, 0, stream>>>(hidden, sid, Ahi, Alo);

  gemm_kernel<0><<<1536, 256, 0, stream>>>(Ahi, Alo, W, b1, X1hi, X1lo, nullptr, nullptr);
  gemm_kernel<1><<<1536, 256, 0, stream>>>(X1hi, X1lo, W + (size_t)NH * NH, b2,
                                           nullptr, nullptr, w3, part);
  finish_kernel<<<NM / 256, 256, 0, stream>>>(part, b3, out);
}

// Round 7
// 235.237 us; speedup vs baseline: 1.4159x; 1.4159x over previous
//
#include <hip/hip_runtime.h>
#include <stdint.h>

#define NB 64
#define NT 512
#define NH 768
#define NS 128
#define NM (NB*NS)   // 8192 rows

typedef _Float16 half8 __attribute__((ext_vector_type(8)));
typedef _Float16 half4 __attribute__((ext_vector_type(4)));
typedef __attribute__((ext_vector_type(4))) float f32x4;

__device__ __forceinline__ float gelu_exact(float x) {
  return 0.5f * x * (1.0f + erff(x * 0.70710678118654752440f));
}

// async global->LDS, 16B per lane; LDS dest is wave-uniform base (HW adds lane*16)
__device__ __forceinline__ void gll16(const void* g, void* l) {
  __builtin_amdgcn_global_load_lds(
      (__attribute__((address_space(1))) unsigned int*)g,
      (__attribute__((address_space(3))) unsigned int*)l,
      16, 0, 0);
}

// ---------------------------------------------------------------------------
// Weight prep: w[k][n] f32 -> blocked f16 layout W[w][n>>4][k>>3][n&15][k&7].
// A B-fragment load (16 n-rows x 8 k) is then ONE 256B-contiguous block;
// a wave's 4 lk4-blocks x 6 nf are 1KB-contiguous bursts (fixes R6's
// 16-scattered-64B-lines-per-load latency problem).
// ---------------------------------------------------------------------------
__global__ void prep_w_kernel(const float* __restrict__ w1, const float* __restrict__ w2,
                              _Float16* __restrict__ W) {
  int id = blockIdx.x * 256 + threadIdx.x;   // 2*96*768 total
  int n  = id % NH;
  int t  = id / NH;
  int kc = t % 96;                           // k-block of 8
  int w  = t / 96;
  const float* src = w ? w2 : w1;
  int k0 = kc * 8;
  half8 h;
#pragma unroll
  for (int i = 0; i < 8; ++i)
    h[i] = (_Float16)src[(size_t)(k0 + i) * NH + n];   // coalesced across n
  const size_t off = ((((size_t)w * 48 + (n >> 4)) * 96 + kc) * 16 + (n & 15)) * 8;
  *(half8*)&W[off] = h;
}

// ---------------------------------------------------------------------------
// Fused pool: segment-mean + f16 hi/lo split, plain row-major store. No atomics.
// grid (12 col-chunks, 64 batches), 256 threads = 16 seg-groups x 16 f32x4-cols.
// ---------------------------------------------------------------------------
__global__ __launch_bounds__(256)
void pool_kernel(const float* __restrict__ hidden, const int* __restrict__ sid,
                 _Float16* __restrict__ Ahi, _Float16* __restrict__ Alo) {
  __shared__ int   s_sid[NT];
  __shared__ short s_e0[NS + 1];
  const int b = blockIdx.y, cc = blockIdx.x;
  const int tid = threadIdx.x;
  for (int t = tid; t < NT; t += 256) s_sid[t] = sid[b * NT + t];
  __syncthreads();
  for (int t = tid; t < NT; t += 256) {
    const int cur  = s_sid[t];
    const int prev = t ? s_sid[t - 1] : -1;
    for (int s = prev + 1; s <= cur; ++s) s_e0[s] = (short)t;   // each s written once
    if (t == NT - 1)
      for (int s = cur + 1; s <= NS; ++s) s_e0[s] = (short)NT;
  }
  __syncthreads();

  const int c4  = tid & 15;           // 16 f32x4 column groups -> 64 cols
  const int sg  = tid >> 4;           // 16 segment groups
  const int col = cc * 64 + c4 * 4;
  const float* hb = hidden + (size_t)b * NT * NH;

  for (int s = sg; s < NS; s += 16) { // 8 segments per thread, strided for balance
    const int e0 = s_e0[s], e1 = s_e0[s + 1];
    f32x4 acc = {0.f, 0.f, 0.f, 0.f};
    for (int t = e0; t < e1; ++t)
      acc += *(const f32x4*)(hb + (size_t)t * NH + col);
    const float inv = 1.0f / (float)((e1 > e0) ? (e1 - e0) : 1);
    const int m = b * NS + s;
    half4 h, l;
#pragma unroll
    for (int j = 0; j < 4; ++j) {
      float x = acc[j] * inv;
      h[j] = (_Float16)x;
      l[j] = (_Float16)(x - (float)h[j]);
    }
    const size_t off = (size_t)m * NH + col;   // plain row-major
    *(half4*)&Ahi[off] = h;
    *(half4*)&Alo[off] = l;
  }
}

// ---------------------------------------------------------------------------
// Fused 3-layer MLP. 256 blocks x 512 threads (8 waves). Block owns 32 rows;
// wave wv owns cols [wv*96, wv*96+96) in BOTH layers (cb = wv*6+nf n16-blocks).
// Layer 1: A (f16 hi/lo) staged LDS (double-buffered, source-XOR swizzle),
//          W1 fragments direct global->VGPR (blocked layout, L2-resident),
//          f16x2 MFMA -> x1 = gelu(.) -> LDS (swizzled, f16 single).
// Layer 2: zero barriers - x1 frags from LDS, W2 direct, f16 MFMA.
// Layer 3: gelu -> dot w3 -> shfl + LDS reduce -> sigmoid -> out.
// x1 never touches global memory.
// ---------------------------------------------------------------------------
__global__ __launch_bounds__(512, 1)
void mlp_kernel(const _Float16* __restrict__ Ahi, const _Float16* __restrict__ Alo,
                const _Float16* __restrict__ Wp,
                const float* __restrict__ b1, const float* __restrict__ b2,
                const float* __restrict__ w3, const float* __restrict__ b3,
                float* __restrict__ out) {
  __shared__ _Float16 sA[2][2][4096];   // [buf][hi/lo][32 rows][128 k] = 32 KB
  __shared__ _Float16 sX[32 * NH];      // x1, swizzled, 48 KB
  __shared__ float    sP[8][32];

  const int tid  = threadIdx.x;
  const int lane = tid & 63;
  const int wv   = tid >> 6;            // 0..7
  const int lr   = lane & 15;
  const int lk4  = lane >> 4;           // 0..3
  const int row0 = blockIdx.x * 32;

  const _Float16* W1 = Wp;
  const _Float16* W2 = Wp + (size_t)NH * NH;

  // stage A hi/lo for K-step kt into buffer b (1KB per gll16 per wave)
  const int   str  = wv * 4 + lk4;                       // staged row 0..31
  const int   scol = (lr * 8) ^ ((str & 7) << 3);        // source-XOR swizzle
#define STAGE(b, kt) {                                                        \
    const size_t src = (size_t)(row0 + str) * NH + (kt) * 128 + scol;         \
    gll16(Ahi + src, &sA[b][0][wv * 512]);                                    \
    gll16(Alo + src, &sA[b][1][wv * 512]); }

  // ---- Layer 1 ----
  f32x4 acc1[2][6] = {};
  STAGE(0, 0);
  __syncthreads();
  for (int kt = 0; kt < 6; ++kt) {
    const int cur = kt & 1;
    if (kt < 5) STAGE(cur ^ 1, kt + 1);
#pragma unroll
    for (int kk = 0; kk < 4; ++kk) {
      half8 bw[6];
#pragma unroll
      for (int nf = 0; nf < 6; ++nf)
        bw[nf] = *(const half8*)(W1 + ((size_t)(wv * 6 + nf) * 96 + kt * 16 + kk * 4 + lk4) * 128 + lr * 8);
#pragma unroll
      for (int mf = 0; mf < 2; ++mf) {
        const int ar = mf * 16 + lr;
        const int ad = ar * 128 + ((kk * 32 + lk4 * 8) ^ ((ar & 7) << 3));
        half8 ah = *(const half8*)&sA[cur][0][ad];
        half8 al = *(const half8*)&sA[cur][1][ad];
#pragma unroll
        for (int nf = 0; nf < 6; ++nf) {
          acc1[mf][nf] = __builtin_amdgcn_mfma_f32_16x16x32_f16(ah, bw[nf], acc1[mf][nf], 0, 0, 0);
          acc1[mf][nf] = __builtin_amdgcn_mfma_f32_16x16x32_f16(al, bw[nf], acc1[mf][nf], 0, 0, 0);
        }
      }
    }
    __syncthreads();   // drains vmcnt -> next buf staged; protects buf reuse
  }

  // layer-1 epilogue: x1 = gelu(acc1 + b1) -> sX (k-XOR swizzled per row)
#pragma unroll
  for (int nf = 0; nf < 6; ++nf) {
    const int col = wv * 96 + nf * 16 + lr;
    const float bv = b1[col];
#pragma unroll
    for (int mf = 0; mf < 2; ++mf)
#pragma unroll
      for (int r = 0; r < 4; ++r) {
        const int row = mf * 16 + lk4 * 4 + r;
        sX[row * NH + (col ^ ((row & 7) << 3))] = (_Float16)gelu_exact(acc1[mf][nf][r] + bv);
      }
  }
  __syncthreads();

  // ---- Layer 2: no barriers ----
  f32x4 acc2[2][6] = {};
#pragma unroll 4
  for (int kb8 = 0; kb8 < 96; kb8 += 4) {   // 24 groups of 32 k
    half8 bw[6];
#pragma unroll
    for (int nf = 0; nf < 6; ++nf)
      bw[nf] = *(const half8*)(W2 + ((size_t)(wv * 6 + nf) * 96 + kb8 + lk4) * 128 + lr * 8);
#pragma unroll
    for (int mf = 0; mf < 2; ++mf) {
      const int ar = mf * 16 + lr;
      half8 a = *(const half8*)&sX[ar * NH + ((kb8 * 8 + lk4 * 8) ^ ((ar & 7) << 3))];
#pragma unroll
      for (int nf = 0; nf < 6; ++nf)
        acc2[mf][nf] = __builtin_amdgcn_mfma_f32_16x16x32_f16(a, bw[nf], acc2[mf][nf], 0, 0, 0);
    }
  }

  // ---- Layer 3: gelu -> dot w3 -> reduce -> sigmoid ----
  float p[2][4] = {};
#pragma unroll
  for (int nf = 0; nf < 6; ++nf) {
    const int col = wv * 96 + nf * 16 + lr;
    const float bv = b2[col], wvv = w3[col];
#pragma unroll
    for (int mf = 0; mf < 2; ++mf)
#pragma unroll
      for (int r = 0; r < 4; ++r)
        p[mf][r] += gelu_exact(acc2[mf][nf][r] + bv) * wvv;
  }
#pragma unroll
  for (int mf = 0; mf < 2; ++mf)
#pragma unroll
    for (int r = 0; r < 4; ++r) {
      float v = p[mf][r];
      v += __shfl_xor(v, 1, 16);
      v += __shfl_xor(v, 2, 16);
      v += __shfl_xor(v, 4, 16);
      v += __shfl_xor(v, 8, 16);
      if (lr == 0) sP[wv][mf * 16 + lk4 * 4 + r] = v;
    }
  __syncthreads();
  if (tid < 32) {
    float s = b3[0];
#pragma unroll
    for (int w = 0; w < 8; ++w) s += sP[w][tid];
    out[row0 + tid] = 1.0f / (1.0f + expf(-s));
  }
#undef STAGE
}

// ---------------------------------------------------------------------------
extern "C" void kernel_launch(void* const* d_in, const int* in_sizes, int n_in,
                              void* d_out, int out_size, void* d_ws, size_t ws_size,
                              hipStream_t stream) {
  (void)in_sizes; (void)n_in; (void)out_size; (void)ws_size;
  const float* hidden = (const float*)d_in[0];
  const int*   sid    = (const int*)d_in[1];
  const float* w1     = (const float*)d_in[2];
  const float* b1     = (const float*)d_in[3];
  const float* w2     = (const float*)d_in[4];
  const float* b2     = (const float*)d_in[5];
  const float* w3     = (const float*)d_in[6];
  const float* b3     = (const float*)d_in[7];
  float* out = (float*)d_out;

  char* p = (char*)d_ws;
  const size_t actE = (size_t)NM * NH;
  _Float16* Ahi = (_Float16*)p; p += actE * 2;
  _Float16* Alo = (_Float16*)p; p += actE * 2;
  _Float16* W   = (_Float16*)p; p += (size_t)2 * NH * NH * 2;

  prep_w_kernel<<<2 * 96 * NH / 256, 256, 0, stream>>>(w1, w2, W);
  pool_kernel<<<dim3(12, NB), 256, 0, stream>>>(hidden, sid, Ahi, Alo);
  mlp_kernel<<<NM / 32, 512, 0, stream>>>(Ahi, Alo, W, b1, b2, w3, b3, out);
}

// Round 8
// 227.051 us; speedup vs baseline: 1.4669x; 1.0361x over previous
//
#include <hip/hip_runtime.h>
#include <stdint.h>

#define NB 64
#define NT 512
#define NH 768
#define NS 128
#define NM (NB*NS)   // 8192 rows

typedef _Float16 half8 __attribute__((ext_vector_type(8)));
typedef _Float16 half4 __attribute__((ext_vector_type(4)));
typedef __attribute__((ext_vector_type(4))) float f32x4;

// gelu(x) = x*Phi(x), Phi via Abramowitz-Stegun 7.1.26 erf (|eps|<=1.5e-7),
// native v_exp_f32 + v_rcp_f32: ~12 VALU + 2 trans vs ~35 VALU for libm erff.
__device__ __forceinline__ float gelu_fast(float x) {
  float ax = fabsf(x) * 0.70710678118654752440f;
  float t  = __builtin_amdgcn_rcpf(1.0f + 0.3275911f * ax);
  float e  = __expf(-ax * ax);
  float poly = t * (0.254829592f + t * (-0.284496736f +
               t * (1.421413741f + t * (-1.453152027f + t * 1.061405429f))));
  float erfv = 1.0f - poly * e;            // erf(ax), ax >= 0
  float phi  = 0.5f * (1.0f + copysignf(erfv, x));
  return x * phi;
}

// async global->LDS, 16B per lane; LDS dest is wave-uniform base (HW adds lane*16)
__device__ __forceinline__ void gll16(const void* g, void* l) {
  __builtin_amdgcn_global_load_lds(
      (__attribute__((address_space(1))) unsigned int*)g,
      (__attribute__((address_space(3))) unsigned int*)l,
      16, 0, 0);
}

// ---------------------------------------------------------------------------
// Weight prep: w[k][n] f32 -> blocked f16 layout W[w][n>>4][k>>3][n&15][k&7].
// B-fragment load (16 n-rows x 8 k) = ONE 256B-contiguous block.
// ---------------------------------------------------------------------------
__global__ void prep_w_kernel(const float* __restrict__ w1, const float* __restrict__ w2,
                              _Float16* __restrict__ W) {
  int id = blockIdx.x * 256 + threadIdx.x;   // 2*96*768 total
  int n  = id % NH;
  int t  = id / NH;
  int kc = t % 96;                           // k-block of 8
  int w  = t / 96;
  const float* src = w ? w2 : w1;
  int k0 = kc * 8;
  half8 h;
#pragma unroll
  for (int i = 0; i < 8; ++i)
    h[i] = (_Float16)src[(size_t)(k0 + i) * NH + n];   // coalesced across n
  const size_t off = ((((size_t)w * 48 + (n >> 4)) * 96 + kc) * 16 + (n & 15)) * 8;
  *(half8*)&W[off] = h;
}

// ---------------------------------------------------------------------------
// Fused pool: segment-mean + f16 hi/lo split, plain row-major store. No atomics.
// grid (12 col-chunks, 64 batches), 256 threads = 16 seg-groups x 16 f32x4-cols.
// ---------------------------------------------------------------------------
__global__ __launch_bounds__(256)
void pool_kernel(const float* __restrict__ hidden, const int* __restrict__ sid,
                 _Float16* __restrict__ Ahi, _Float16* __restrict__ Alo) {
  __shared__ int   s_sid[NT];
  __shared__ short s_e0[NS + 1];
  const int b = blockIdx.y, cc = blockIdx.x;
  const int tid = threadIdx.x;
  for (int t = tid; t < NT; t += 256) s_sid[t] = sid[b * NT + t];
  __syncthreads();
  for (int t = tid; t < NT; t += 256) {
    const int cur  = s_sid[t];
    const int prev = t ? s_sid[t - 1] : -1;
    for (int s = prev + 1; s <= cur; ++s) s_e0[s] = (short)t;   // each s written once
    if (t == NT - 1)
      for (int s = cur + 1; s <= NS; ++s) s_e0[s] = (short)NT;
  }
  __syncthreads();

  const int c4  = tid & 15;           // 16 f32x4 column groups -> 64 cols
  const int sg  = tid >> 4;           // 16 segment groups
  const int col = cc * 64 + c4 * 4;
  const float* hb = hidden + (size_t)b * NT * NH;

  for (int s = sg; s < NS; s += 16) { // 8 segments per thread, strided for balance
    const int e0 = s_e0[s], e1 = s_e0[s + 1];
    f32x4 acc = {0.f, 0.f, 0.f, 0.f};
    for (int t = e0; t < e1; ++t)
      acc += *(const f32x4*)(hb + (size_t)t * NH + col);
    const float inv = 1.0f / (float)((e1 > e0) ? (e1 - e0) : 1);
    const int m = b * NS + s;
    half4 h, l;
#pragma unroll
    for (int j = 0; j < 4; ++j) {
      float x = acc[j] * inv;
      h[j] = (_Float16)x;
      l[j] = (_Float16)(x - (float)h[j]);
    }
    const size_t off = (size_t)m * NH + col;   // plain row-major
    *(half4*)&Ahi[off] = h;
    *(half4*)&Alo[off] = l;
  }
}

// ---------------------------------------------------------------------------
// Fused 3-layer MLP. 256 blocks x 512 threads (8 waves), 32 rows/block,
// wave wv owns cols [wv*96, wv*96+96) in both layers.
// R8: single-buffered sA + sP aliased -> 64KB LDS -> 2 blocks/CU (4 waves/SIMD,
// cross-block latency hiding); 1-deep register prefetch of W fragments;
// gelu_fast epilogues.
// ---------------------------------------------------------------------------
__global__ __launch_bounds__(512, 4)
void mlp_kernel(const _Float16* __restrict__ Ahi, const _Float16* __restrict__ Alo,
                const _Float16* __restrict__ Wp,
                const float* __restrict__ b1, const float* __restrict__ b2,
                const float* __restrict__ w3, const float* __restrict__ b3,
                float* __restrict__ out) {
  __shared__ _Float16 sA[2][4096];      // [hi/lo][32 rows][128 k] = 16 KB (single buf)
  __shared__ _Float16 sX[32 * NH];      // x1, swizzled, 48 KB
  float (*sP)[32] = (float(*)[32])&sA[0][0];   // sA dead after layer 1

  const int tid  = threadIdx.x;
  const int lane = tid & 63;
  const int wv   = tid >> 6;            // 0..7
  const int lr   = lane & 15;
  const int lk4  = lane >> 4;           // 0..3
  const int row0 = blockIdx.x * 32;

  const _Float16* W1 = Wp;
  const _Float16* W2 = Wp + (size_t)NH * NH;

  const int str  = wv * 4 + lk4;                       // staged row 0..31
  const int scol = (lr * 8) ^ ((str & 7) << 3);        // source-XOR swizzle
#define STAGE(kt) {                                                           \
    const size_t src = (size_t)(row0 + str) * NH + (kt) * 128 + scol;         \
    gll16(Ahi + src, &sA[0][wv * 512]);                                       \
    gll16(Alo + src, &sA[1][wv * 512]); }

  // ---- Layer 1 ----
  f32x4 acc1[2][6] = {};
  STAGE(0);
  __syncthreads();
  for (int kt = 0; kt < 6; ++kt) {
    half8 bw[6], bwn[6];
#pragma unroll
    for (int nf = 0; nf < 6; ++nf)
      bw[nf] = *(const half8*)(W1 + ((size_t)(wv * 6 + nf) * 96 + kt * 16 + lk4) * 128 + lr * 8);
#pragma unroll
    for (int kk = 0; kk < 4; ++kk) {
      if (kk < 3) {
#pragma unroll
        for (int nf = 0; nf < 6; ++nf)
          bwn[nf] = *(const half8*)(W1 + ((size_t)(wv * 6 + nf) * 96 + kt * 16 + (kk + 1) * 4 + lk4) * 128 + lr * 8);
      }
#pragma unroll
      for (int mf = 0; mf < 2; ++mf) {
        const int ar = mf * 16 + lr;
        const int ad = ar * 128 + ((kk * 32 + lk4 * 8) ^ ((ar & 7) << 3));
        half8 ah = *(const half8*)&sA[0][ad];
        half8 al = *(const half8*)&sA[1][ad];
#pragma unroll
        for (int nf = 0; nf < 6; ++nf) {
          acc1[mf][nf] = __builtin_amdgcn_mfma_f32_16x16x32_f16(ah, bw[nf], acc1[mf][nf], 0, 0, 0);
          acc1[mf][nf] = __builtin_amdgcn_mfma_f32_16x16x32_f16(al, bw[nf], acc1[mf][nf], 0, 0, 0);
        }
      }
#pragma unroll
      for (int nf = 0; nf < 6; ++nf) bw[nf] = bwn[nf];
    }
    __syncthreads();                    // all waves done reading sA
    if (kt < 5) {
      STAGE(kt + 1);
      __syncthreads();                  // drains vmcnt -> sA valid
    }
  }

  // layer-1 epilogue: x1 = gelu(acc1 + b1) -> sX (k-XOR swizzled per row)
#pragma unroll
  for (int nf = 0; nf < 6; ++nf) {
    const int col = wv * 96 + nf * 16 + lr;
    const float bv = b1[col];
#pragma unroll
    for (int mf = 0; mf < 2; ++mf)
#pragma unroll
      for (int r = 0; r < 4; ++r) {
        const int row = mf * 16 + lk4 * 4 + r;
        sX[row * NH + (col ^ ((row & 7) << 3))] = (_Float16)gelu_fast(acc1[mf][nf][r] + bv);
      }
  }
  __syncthreads();

  // ---- Layer 2: no barriers, 1-deep W prefetch ----
  f32x4 acc2[2][6] = {};
  half8 bw2[6], bw2n[6];
#pragma unroll
  for (int nf = 0; nf < 6; ++nf)
    bw2[nf] = *(const half8*)(W2 + ((size_t)(wv * 6 + nf) * 96 + lk4) * 128 + lr * 8);
  for (int g = 0; g < 24; ++g) {        // 24 groups of k32
    if (g < 23) {
#pragma unroll
      for (int nf = 0; nf < 6; ++nf)
        bw2n[nf] = *(const half8*)(W2 + ((size_t)(wv * 6 + nf) * 96 + (g + 1) * 4 + lk4) * 128 + lr * 8);
    }
    const int koff = g * 32 + lk4 * 8;
#pragma unroll
    for (int mf = 0; mf < 2; ++mf) {
      const int ar = mf * 16 + lr;
      half8 a = *(const half8*)&sX[ar * NH + (koff ^ ((ar & 7) << 3))];
#pragma unroll
      for (int nf = 0; nf < 6; ++nf)
        acc2[mf][nf] = __builtin_amdgcn_mfma_f32_16x16x32_f16(a, bw2[nf], acc2[mf][nf], 0, 0, 0);
    }
#pragma unroll
    for (int nf = 0; nf < 6; ++nf) bw2[nf] = bw2n[nf];
  }

  // ---- Layer 3: gelu -> dot w3 -> reduce -> sigmoid ----
  float p[2][4] = {};
#pragma unroll
  for (int nf = 0; nf < 6; ++nf) {
    const int col = wv * 96 + nf * 16 + lr;
    const float bv = b2[col], wvv = w3[col];
#pragma unroll
    for (int mf = 0; mf < 2; ++mf)
#pragma unroll
      for (int r = 0; r < 4; ++r)
        p[mf][r] += gelu_fast(acc2[mf][nf][r] + bv) * wvv;
  }
#pragma unroll
  for (int mf = 0; mf < 2; ++mf)
#pragma unroll
    for (int r = 0; r < 4; ++r) {
      float v = p[mf][r];
      v += __shfl_xor(v, 1, 16);
      v += __shfl_xor(v, 2, 16);
      v += __shfl_xor(v, 4, 16);
      v += __shfl_xor(v, 8, 16);
      if (lr == 0) sP[wv][mf * 16 + lk4 * 4 + r] = v;
    }
  __syncthreads();
  if (tid < 32) {
    float s = b3[0];
#pragma unroll
    for (int w = 0; w < 8; ++w) s += sP[w][tid];
    out[row0 + tid] = 1.0f / (1.0f + expf(-s));
  }
#undef STAGE
}

// ---------------------------------------------------------------------------
extern "C" void kernel_launch(void* const* d_in, const int* in_sizes, int n_in,
                              void* d_out, int out_size, void* d_ws, size_t ws_size,
                              hipStream_t stream) {
  (void)in_sizes; (void)n_in; (void)out_size; (void)ws_size;
  const float* hidden = (const float*)d_in[0];
  const int*   sid    = (const int*)d_in[1];
  const float* w1     = (const float*)d_in[2];
  const float* b1     = (const float*)d_in[3];
  const float* w2     = (const float*)d_in[4];
  const float* b2     = (const float*)d_in[5];
  const float* w3     = (const float*)d_in[6];
  const float* b3     = (const float*)d_in[7];
  float* out = (float*)d_out;

  char* p = (char*)d_ws;
  const size_t actE = (size_t)NM * NH;
  _Float16* Ahi = (_Float16*)p; p += actE * 2;
  _Float16* Alo = (_Float16*)p; p += actE * 2;
  _Float16* W   = (_Float16*)p; p += (size_t)2 * NH * NH * 2;

  prep_w_kernel<<<2 * 96 * NH / 256, 256, 0, stream>>>(w1, w2, W);
  pool_kernel<<<dim3(12, NB), 256, 0, stream>>>(hidden, sid, Ahi, Alo);
  mlp_kernel<<<NM / 32, 512, 0, stream>>>(Ahi, Alo, W, b1, b2, w3, b3, out);
}

// Round 9
// 226.118 us; speedup vs baseline: 1.4730x; 1.0041x over previous
//
#include <hip/hip_runtime.h>
#include <stdint.h>

#define NB 64
#define NT 512
#define NH 768
#define NS 128
#define NM (NB*NS)   // 8192 rows

typedef _Float16 half8 __attribute__((ext_vector_type(8)));
typedef _Float16 half4 __attribute__((ext_vector_type(4)));
typedef __attribute__((ext_vector_type(4))) float f32x4;

// gelu(x) = x*Phi(x), Phi via Abramowitz-Stegun 7.1.26 erf (|eps|<=1.5e-7),
// native v_exp_f32 + v_rcp_f32: ~12 VALU + 2 trans vs ~35 VALU for libm erff.
__device__ __forceinline__ float gelu_fast(float x) {
  float ax = fabsf(x) * 0.70710678118654752440f;
  float t  = __builtin_amdgcn_rcpf(1.0f + 0.3275911f * ax);
  float e  = __expf(-ax * ax);
  float poly = t * (0.254829592f + t * (-0.284496736f +
               t * (1.421413741f + t * (-1.453152027f + t * 1.061405429f))));
  float erfv = 1.0f - poly * e;            // erf(ax), ax >= 0
  float phi  = 0.5f * (1.0f + copysignf(erfv, x));
  return x * phi;
}

// async global->LDS, 16B per lane; LDS dest is wave-uniform base (HW adds lane*16)
__device__ __forceinline__ void gll16(const void* g, void* l) {
  __builtin_amdgcn_global_load_lds(
      (__attribute__((address_space(1))) unsigned int*)g,
      (__attribute__((address_space(3))) unsigned int*)l,
      16, 0, 0);
}

// ---------------------------------------------------------------------------
// Weight prep: w[k][n] f32 -> blocked f16 layout W[w][n>>4][k>>3][n&15][k&7].
// B-fragment load (16 n-rows x 8 k) = ONE 256B-contiguous block.
// ---------------------------------------------------------------------------
__global__ void prep_w_kernel(const float* __restrict__ w1, const float* __restrict__ w2,
                              _Float16* __restrict__ W) {
  int id = blockIdx.x * 256 + threadIdx.x;   // 2*96*768 total
  int n  = id % NH;
  int t  = id / NH;
  int kc = t % 96;                           // k-block of 8
  int w  = t / 96;
  const float* src = w ? w2 : w1;
  int k0 = kc * 8;
  half8 h;
#pragma unroll
  for (int i = 0; i < 8; ++i)
    h[i] = (_Float16)src[(size_t)(k0 + i) * NH + n];   // coalesced across n
  const size_t off = ((((size_t)w * 48 + (n >> 4)) * 96 + kc) * 16 + (n & 15)) * 8;
  *(half8*)&W[off] = h;
}

// ---------------------------------------------------------------------------
// Pool v3: block = (batch, 8-segment group). Sorted ids => block's tokens are
// ONE CONTIGUOUS chunk of hidden; 192 threads read full 3072B rows
// (3 x 1KB wave bursts, sequential). Per-segment accumulate in VGPRs,
// wave-uniform flush = plain LDS store (segment wholly inside block -> no
// atomics, no RMW). 1-deep load prefetch for MLP. Divide+f16split+store.
// Grid (16,64) = 1024 blocks -> 4 blocks/CU.
// ---------------------------------------------------------------------------
__global__ __launch_bounds__(192)
void pool_kernel(const float* __restrict__ hidden, const int* __restrict__ sid,
                 _Float16* __restrict__ Ahi, _Float16* __restrict__ Alo) {
  __shared__ int   s_sid[NT];
  __shared__ short s_e0[NS + 1];
  __shared__ float sAcc[8][NH];       // 24 KB
  const int b = blockIdx.y, g = blockIdx.x;   // segments g*8 .. g*8+7
  const int tid = threadIdx.x;

  for (int t = tid; t < NT; t += 192) s_sid[t] = sid[b * NT + t];
  __syncthreads();
  for (int t = tid; t < NT; t += 192) {
    const int cur  = s_sid[t];
    const int prev = t ? s_sid[t - 1] : -1;
    for (int s = prev + 1; s <= cur; ++s) s_e0[s] = (short)t;   // each s written once
    if (t == NT - 1)
      for (int s = cur + 1; s <= NS; ++s) s_e0[s] = (short)NT;
  }
  // zero the segment accumulator (8x768 f32 / 192 thr = 8 f32x4 each)
#pragma unroll
  for (int i = 0; i < 8; ++i)
    *(f32x4*)&sAcc[0][(i * 192 + tid) * 4] = (f32x4){0.f, 0.f, 0.f, 0.f};
  __syncthreads();

  const int s0 = g * 8;
  const int t0 = s_e0[s0], t1 = s_e0[s0 + 8];
  const int col = tid * 4;                    // 192 threads x f32x4 = 768 cols
  const float* hb = hidden + (size_t)b * NT * NH;

  f32x4 acc = {0.f, 0.f, 0.f, 0.f};
  int cur = (t0 < t1) ? s_sid[t0] : -1;
  f32x4 nxt;
  if (t0 < t1) nxt = *(const f32x4*)(hb + (size_t)t0 * NH + col);
  for (int t = t0; t < t1; ++t) {
    f32x4 v = nxt;
    if (t + 1 < t1) nxt = *(const f32x4*)(hb + (size_t)(t + 1) * NH + col);  // prefetch
    const int s = s_sid[t];
    if (s != cur) {                           // wave-uniform branch
      *(f32x4*)&sAcc[cur - s0][col] = acc;    // plain store: sole writer
      acc = (f32x4){0.f, 0.f, 0.f, 0.f};
      cur = s;
    }
    acc += v;
  }
  if (cur >= 0) *(f32x4*)&sAcc[cur - s0][col] = acc;
  __syncthreads();

  // epilogue: mean + f16 hi/lo split, plain row-major store
#pragma unroll
  for (int s = 0; s < 8; ++s) {
    const int gs = s0 + s;
    const int cnt = s_e0[gs + 1] - s_e0[gs];
    const float inv = 1.0f / (float)(cnt > 0 ? cnt : 1);
    f32x4 v = *(const f32x4*)&sAcc[s][col];
    half4 h, l;
#pragma unroll
    for (int j = 0; j < 4; ++j) {
      float x = v[j] * inv;
      h[j] = (_Float16)x;
      l[j] = (_Float16)(x - (float)h[j]);
    }
    const size_t off = (size_t)(b * NS + gs) * NH + col;
    *(half4*)&Ahi[off] = h;
    *(half4*)&Alo[off] = l;
  }
}

// ---------------------------------------------------------------------------
// Fused 3-layer MLP (unchanged from R8). 256 blocks x 512 threads, 32 rows/blk.
// ---------------------------------------------------------------------------
__global__ __launch_bounds__(512, 4)
void mlp_kernel(const _Float16* __restrict__ Ahi, const _Float16* __restrict__ Alo,
                const _Float16* __restrict__ Wp,
                const float* __restrict__ b1, const float* __restrict__ b2,
                const float* __restrict__ w3, const float* __restrict__ b3,
                float* __restrict__ out) {
  __shared__ _Float16 sA[2][4096];      // [hi/lo][32 rows][128 k] = 16 KB (single buf)
  __shared__ _Float16 sX[32 * NH];      // x1, swizzled, 48 KB
  float (*sP)[32] = (float(*)[32])&sA[0][0];   // sA dead after layer 1

  const int tid  = threadIdx.x;
  const int lane = tid & 63;
  const int wv   = tid >> 6;            // 0..7
  const int lr   = lane & 15;
  const int lk4  = lane >> 4;           // 0..3
  const int row0 = blockIdx.x * 32;

  const _Float16* W1 = Wp;
  const _Float16* W2 = Wp + (size_t)NH * NH;

  const int str  = wv * 4 + lk4;                       // staged row 0..31
  const int scol = (lr * 8) ^ ((str & 7) << 3);        // source-XOR swizzle
#define STAGE(kt) {                                                           \
    const size_t src = (size_t)(row0 + str) * NH + (kt) * 128 + scol;         \
    gll16(Ahi + src, &sA[0][wv * 512]);                                       \
    gll16(Alo + src, &sA[1][wv * 512]); }

  // ---- Layer 1 ----
  f32x4 acc1[2][6] = {};
  STAGE(0);
  __syncthreads();
  for (int kt = 0; kt < 6; ++kt) {
    half8 bw[6], bwn[6];
#pragma unroll
    for (int nf = 0; nf < 6; ++nf)
      bw[nf] = *(const half8*)(W1 + ((size_t)(wv * 6 + nf) * 96 + kt * 16 + lk4) * 128 + lr * 8);
#pragma unroll
    for (int kk = 0; kk < 4; ++kk) {
      if (kk < 3) {
#pragma unroll
        for (int nf = 0; nf < 6; ++nf)
          bwn[nf] = *(const half8*)(W1 + ((size_t)(wv * 6 + nf) * 96 + kt * 16 + (kk + 1) * 4 + lk4) * 128 + lr * 8);
      }
#pragma unroll
      for (int mf = 0; mf < 2; ++mf) {
        const int ar = mf * 16 + lr;
        const int ad = ar * 128 + ((kk * 32 + lk4 * 8) ^ ((ar & 7) << 3));
        half8 ah = *(const half8*)&sA[0][ad];
        half8 al = *(const half8*)&sA[1][ad];
#pragma unroll
        for (int nf = 0; nf < 6; ++nf) {
          acc1[mf][nf] = __builtin_amdgcn_mfma_f32_16x16x32_f16(ah, bw[nf], acc1[mf][nf], 0, 0, 0);
          acc1[mf][nf] = __builtin_amdgcn_mfma_f32_16x16x32_f16(al, bw[nf], acc1[mf][nf], 0, 0, 0);
        }
      }
#pragma unroll
      for (int nf = 0; nf < 6; ++nf) bw[nf] = bwn[nf];
    }
    __syncthreads();                    // all waves done reading sA
    if (kt < 5) {
      STAGE(kt + 1);
      __syncthreads();                  // drains vmcnt -> sA valid
    }
  }

  // layer-1 epilogue: x1 = gelu(acc1 + b1) -> sX (k-XOR swizzled per row)
#pragma unroll
  for (int nf = 0; nf < 6; ++nf) {
    const int col = wv * 96 + nf * 16 + lr;
    const float bv = b1[col];
#pragma unroll
    for (int mf = 0; mf < 2; ++mf)
#pragma unroll
      for (int r = 0; r < 4; ++r) {
        const int row = mf * 16 + lk4 * 4 + r;
        sX[row * NH + (col ^ ((row & 7) << 3))] = (_Float16)gelu_fast(acc1[mf][nf][r] + bv);
      }
  }
  __syncthreads();

  // ---- Layer 2: no barriers, 1-deep W prefetch ----
  f32x4 acc2[2][6] = {};
  half8 bw2[6], bw2n[6];
#pragma unroll
  for (int nf = 0; nf < 6; ++nf)
    bw2[nf] = *(const half8*)(W2 + ((size_t)(wv * 6 + nf) * 96 + lk4) * 128 + lr * 8);
  for (int g = 0; g < 24; ++g) {        // 24 groups of k32
    if (g < 23) {
#pragma unroll
      for (int nf = 0; nf < 6; ++nf)
        bw2n[nf] = *(const half8*)(W2 + ((size_t)(wv * 6 + nf) * 96 + (g + 1) * 4 + lk4) * 128 + lr * 8);
    }
    const int koff = g * 32 + lk4 * 8;
#pragma unroll
    for (int mf = 0; mf < 2; ++mf) {
      const int ar = mf * 16 + lr;
      half8 a = *(const half8*)&sX[ar * NH + (koff ^ ((ar & 7) << 3))];
#pragma unroll
      for (int nf = 0; nf < 6; ++nf)
        acc2[mf][nf] = __builtin_amdgcn_mfma_f32_16x16x32_f16(a, bw2[nf], acc2[mf][nf], 0, 0, 0);
    }
#pragma unroll
    for (int nf = 0; nf < 6; ++nf) bw2[nf] = bw2n[nf];
  }

  // ---- Layer 3: gelu -> dot w3 -> reduce -> sigmoid ----
  float p[2][4] = {};
#pragma unroll
  for (int nf = 0; nf < 6; ++nf) {
    const int col = wv * 96 + nf * 16 + lr;
    const float bv = b2[col], wvv = w3[col];
#pragma unroll
    for (int mf = 0; mf < 2; ++mf)
#pragma unroll
      for (int r = 0; r < 4; ++r)
        p[mf][r] += gelu_fast(acc2[mf][nf][r] + bv) * wvv;
  }
#pragma unroll
  for (int mf = 0; mf < 2; ++mf)
#pragma unroll
    for (int r = 0; r < 4; ++r) {
      float v = p[mf][r];
      v += __shfl_xor(v, 1, 16);
      v += __shfl_xor(v, 2, 16);
      v += __shfl_xor(v, 4, 16);
      v += __shfl_xor(v, 8, 16);
      if (lr == 0) sP[wv][mf * 16 + lk4 * 4 + r] = v;
    }
  __syncthreads();
  if (tid < 32) {
    float s = b3[0];
#pragma unroll
    for (int w = 0; w < 8; ++w) s += sP[w][tid];
    out[row0 + tid] = 1.0f / (1.0f + expf(-s));
  }
#undef STAGE
}

// ---------------------------------------------------------------------------
extern "C" void kernel_launch(void* const* d_in, const int* in_sizes, int n_in,
                              void* d_out, int out_size, void* d_ws, size_t ws_size,
                              hipStream_t stream) {
  (void)in_sizes; (void)n_in; (void)out_size; (void)ws_size;
  const float* hidden = (const float*)d_in[0];
  const int*   sid    = (const int*)d_in[1];
  const float* w1     = (const float*)d_in[2];
  const float* b1     = (const float*)d_in[3];
  const float* w2     = (const float*)d_in[4];
  const float* b2     = (const float*)d_in[5];
  const float* w3     = (const float*)d_in[6];
  const float* b3     = (const float*)d_in[7];
  float* out = (float*)d_out;

  char* p = (char*)d_ws;
  const size_t actE = (size_t)NM * NH;
  _Float16* Ahi = (_Float16*)p; p += actE * 2;
  _Float16* Alo = (_Float16*)p; p += actE * 2;
  _Float16* W   = (_Float16*)p; p += (size_t)2 * NH * NH * 2;

  prep_w_kernel<<<2 * 96 * NH / 256, 256, 0, stream>>>(w1, w2, W);
  pool_kernel<<<dim3(16, NB), 192, 0, stream>>>(hidden, sid, Ahi, Alo);
  mlp_kernel<<<NM / 32, 512, 0, stream>>>(Ahi, Alo, W, b1, b2, w3, b3, out);
}

// Round 11
// 216.417 us; speedup vs baseline: 1.5390x; 1.0448x over previous
//
#include <hip/hip_runtime.h>
#include <stdint.h>

#define NB 64
#define NT 512
#define NH 768
#define NS 128
#define NM (NB*NS)   // 8192 rows

typedef _Float16 half8 __attribute__((ext_vector_type(8)));
typedef _Float16 half4 __attribute__((ext_vector_type(4)));
typedef __attribute__((ext_vector_type(4))) float f32x4;

// gelu(x) = x*Phi(x), Phi via Abramowitz-Stegun 7.1.26 erf (|eps|<=1.5e-7),
// native v_exp_f32 + v_rcp_f32: ~12 VALU + 2 trans vs ~35 VALU for libm erff.
__device__ __forceinline__ float gelu_fast(float x) {
  float ax = fabsf(x) * 0.70710678118654752440f;
  float t  = __builtin_amdgcn_rcpf(1.0f + 0.3275911f * ax);
  float e  = __expf(-ax * ax);
  float poly = t * (0.254829592f + t * (-0.284496736f +
               t * (1.421413741f + t * (-1.453152027f + t * 1.061405429f))));
  float erfv = 1.0f - poly * e;            // erf(ax), ax >= 0
  float phi  = 0.5f * (1.0f + copysignf(erfv, x));
  return x * phi;
}

// async global->LDS, 16B per lane; LDS dest is wave-uniform base (HW adds lane*16)
__device__ __forceinline__ void gll16(const void* g, void* l) {
  __builtin_amdgcn_global_load_lds(
      (__attribute__((address_space(1))) unsigned int*)g,
      (__attribute__((address_space(3))) unsigned int*)l,
      16, 0, 0);
}

// ---------------------------------------------------------------------------
// Weight prep: w[k][n] f32 -> blocked f16 layout W[w][n>>4][k>>3][n&15][k&7].
// B-fragment load (16 n-rows x 8 k) = ONE 256B-contiguous block.
// ---------------------------------------------------------------------------
__global__ void prep_w_kernel(const float* __restrict__ w1, const float* __restrict__ w2,
                              _Float16* __restrict__ W) {
  int id = blockIdx.x * 256 + threadIdx.x;   // 2*96*768 total
  int n  = id % NH;
  int t  = id / NH;
  int kc = t % 96;                           // k-block of 8
  int w  = t / 96;
  const float* src = w ? w2 : w1;
  int k0 = kc * 8;
  half8 h;
#pragma unroll
  for (int i = 0; i < 8; ++i)
    h[i] = (_Float16)src[(size_t)(k0 + i) * NH + n];   // coalesced across n
  const size_t off = ((((size_t)w * 48 + (n >> 4)) * 96 + kc) * 16 + (n & 15)) * 8;
  *(half8*)&W[off] = h;
}

// ---------------------------------------------------------------------------
// Pool v4: block = (batch, 8-segment group); contiguous token chunk.
// R10: D=8 static register ring of in-flight f32x4 loads (was 1-deep -> one
// outstanding load/thread -> latency-bound at ~1.3 TB/s). All ring indices
// compile-time (rule #20). Issue path branch-free (clamped address).
// ---------------------------------------------------------------------------
__global__ __launch_bounds__(192)
void pool_kernel(const float* __restrict__ hidden, const int* __restrict__ sid,
                 _Float16* __restrict__ Ahi, _Float16* __restrict__ Alo) {
  __shared__ int   s_sid[NT];
  __shared__ short s_e0[NS + 1];
  __shared__ float sAcc[8][NH];       // 24 KB
  const int b = blockIdx.y, g = blockIdx.x;   // segments g*8 .. g*8+7
  const int tid = threadIdx.x;

  for (int t = tid; t < NT; t += 192) s_sid[t] = sid[b * NT + t];
  __syncthreads();
  for (int t = tid; t < NT; t += 192) {
    const int cur  = s_sid[t];
    const int prev = t ? s_sid[t - 1] : -1;
    for (int s = prev + 1; s <= cur; ++s) s_e0[s] = (short)t;   // each s written once
    if (t == NT - 1)
      for (int s = cur + 1; s <= NS; ++s) s_e0[s] = (short)NT;
  }
  // zero the segment accumulator (8x768 f32 / 192 thr = 8 f32x4 each)
#pragma unroll
  for (int i = 0; i < 8; ++i)
    *(f32x4*)&sAcc[0][(i * 192 + tid) * 4] = (f32x4){0.f, 0.f, 0.f, 0.f};
  __syncthreads();

  const int s0 = g * 8;
  const int t0 = s_e0[s0], t1 = s_e0[s0 + 8];
  const int col = tid * 4;                    // 192 threads x f32x4 = 768 cols
  const float* hb = hidden + (size_t)b * NT * NH + col;

  if (t1 > t0) {
    constexpr int D = 8;
    f32x4 buf[D];
    // prologue: fill the ring (clamped indices; clamped slots never consumed)
#pragma unroll
    for (int j = 0; j < D; ++j) {
      int tj = t0 + j; if (tj >= t1) tj = t1 - 1;
      buf[j] = *(const f32x4*)(hb + (size_t)tj * NH);
    }
    f32x4 acc = {0.f, 0.f, 0.f, 0.f};
    int cur = s_sid[t0];
    int t = t0;
    for (; t + D <= t1; t += D) {
#pragma unroll
      for (int j = 0; j < D; ++j) {
        f32x4 v = buf[j];
        int tn = t + j + D; if (tn >= t1) tn = t1 - 1;   // branch-free issue
        buf[j] = *(const f32x4*)(hb + (size_t)tn * NH);  // keep D loads in flight
        const int s = s_sid[t + j];
        if (s != cur) {                       // block-uniform branch
          *(f32x4*)&sAcc[cur - s0][col] = acc;  // plain store: sole writer
          acc = (f32x4){0.f, 0.f, 0.f, 0.f};
          cur = s;
        }
        acc += v;
      }
    }
    // epilogue: remaining < D tokens are already in the ring
#pragma unroll
    for (int j = 0; j < D; ++j) {
      if (t + j < t1) {
        f32x4 v = buf[j];
        const int s = s_sid[t + j];
        if (s != cur) {
          *(f32x4*)&sAcc[cur - s0][col] = acc;
          acc = (f32x4){0.f, 0.f, 0.f, 0.f};
          cur = s;
        }
        acc += v;
      }
    }
    *(f32x4*)&sAcc[cur - s0][col] = acc;
  }
  __syncthreads();

  // epilogue: mean + f16 hi/lo split, plain row-major store
#pragma unroll
  for (int s = 0; s < 8; ++s) {
    const int gs = s0 + s;
    const int cnt = s_e0[gs + 1] - s_e0[gs];
    const float inv = 1.0f / (float)(cnt > 0 ? cnt : 1);
    f32x4 v = *(const f32x4*)&sAcc[s][col];
    half4 h, l;
#pragma unroll
    for (int j = 0; j < 4; ++j) {
      float x = v[j] * inv;
      h[j] = (_Float16)x;
      l[j] = (_Float16)(x - (float)h[j]);
    }
    const size_t off = (size_t)(b * NS + gs) * NH + col;
    *(half4*)&Ahi[off] = h;
    *(half4*)&Alo[off] = l;
  }
}

// ---------------------------------------------------------------------------
// Fused 3-layer MLP (unchanged from R8). 256 blocks x 512 threads, 32 rows/blk.
// ---------------------------------------------------------------------------
__global__ __launch_bounds__(512, 4)
void mlp_kernel(const _Float16* __restrict__ Ahi, const _Float16* __restrict__ Alo,
                const _Float16* __restrict__ Wp,
                const float* __restrict__ b1, const float* __restrict__ b2,
                const float* __restrict__ w3, const float* __restrict__ b3,
                float* __restrict__ out) {
  __shared__ _Float16 sA[2][4096];      // [hi/lo][32 rows][128 k] = 16 KB (single buf)
  __shared__ _Float16 sX[32 * NH];      // x1, swizzled, 48 KB
  float (*sP)[32] = (float(*)[32])&sA[0][0];   // sA dead after layer 1

  const int tid  = threadIdx.x;
  const int lane = tid & 63;
  const int wv   = tid >> 6;            // 0..7
  const int lr   = lane & 15;
  const int lk4  = lane >> 4;           // 0..3
  const int row0 = blockIdx.x * 32;

  const _Float16* W1 = Wp;
  const _Float16* W2 = Wp + (size_t)NH * NH;

  const int str  = wv * 4 + lk4;                       // staged row 0..31
  const int scol = (lr * 8) ^ ((str & 7) << 3);        // source-XOR swizzle
#define STAGE(kt) {                                                           \
    const size_t src = (size_t)(row0 + str) * NH + (kt) * 128 + scol;         \
    gll16(Ahi + src, &sA[0][wv * 512]);                                       \
    gll16(Alo + src, &sA[1][wv * 512]); }

  // ---- Layer 1 ----
  f32x4 acc1[2][6] = {};
  STAGE(0);
  __syncthreads();
  for (int kt = 0; kt < 6; ++kt) {
    half8 bw[6], bwn[6];
#pragma unroll
    for (int nf = 0; nf < 6; ++nf)
      bw[nf] = *(const half8*)(W1 + ((size_t)(wv * 6 + nf) * 96 + kt * 16 + lk4) * 128 + lr * 8);
#pragma unroll
    for (int kk = 0; kk < 4; ++kk) {
      if (kk < 3) {
#pragma unroll
        for (int nf = 0; nf < 6; ++nf)
          bwn[nf] = *(const half8*)(W1 + ((size_t)(wv * 6 + nf) * 96 + kt * 16 + (kk + 1) * 4 + lk4) * 128 + lr * 8);
      }
#pragma unroll
      for (int mf = 0; mf < 2; ++mf) {
        const int ar = mf * 16 + lr;
        const int ad = ar * 128 + ((kk * 32 + lk4 * 8) ^ ((ar & 7) << 3));
        half8 ah = *(const half8*)&sA[0][ad];
        half8 al = *(const half8*)&sA[1][ad];
#pragma unroll
        for (int nf = 0; nf < 6; ++nf) {
          acc1[mf][nf] = __builtin_amdgcn_mfma_f32_16x16x32_f16(ah, bw[nf], acc1[mf][nf], 0, 0, 0);
          acc1[mf][nf] = __builtin_amdgcn_mfma_f32_16x16x32_f16(al, bw[nf], acc1[mf][nf], 0, 0, 0);
        }
      }
#pragma unroll
      for (int nf = 0; nf < 6; ++nf) bw[nf] = bwn[nf];
    }
    __syncthreads();                    // all waves done reading sA
    if (kt < 5) {
      STAGE(kt + 1);
      __syncthreads();                  // drains vmcnt -> sA valid
    }
  }

  // layer-1 epilogue: x1 = gelu(acc1 + b1) -> sX (k-XOR swizzled per row)
#pragma unroll
  for (int nf = 0; nf < 6; ++nf) {
    const int col = wv * 96 + nf * 16 + lr;
    const float bv = b1[col];
#pragma unroll
    for (int mf = 0; mf < 2; ++mf)
#pragma unroll
      for (int r = 0; r < 4; ++r) {
        const int row = mf * 16 + lk4 * 4 + r;
        sX[row * NH + (col ^ ((row & 7) << 3))] = (_Float16)gelu_fast(acc1[mf][nf][r] + bv);
      }
  }
  __syncthreads();

  // ---- Layer 2: no barriers, 1-deep W prefetch ----
  f32x4 acc2[2][6] = {};
  half8 bw2[6], bw2n[6];
#pragma unroll
  for (int nf = 0; nf < 6; ++nf)
    bw2[nf] = *(const half8*)(W2 + ((size_t)(wv * 6 + nf) * 96 + lk4) * 128 + lr * 8);
  for (int g = 0; g < 24; ++g) {        // 24 groups of k32
    if (g < 23) {
#pragma unroll
      for (int nf = 0; nf < 6; ++nf)
        bw2n[nf] = *(const half8*)(W2 + ((size_t)(wv * 6 + nf) * 96 + (g + 1) * 4 + lk4) * 128 + lr * 8);
    }
    const int koff = g * 32 + lk4 * 8;
#pragma unroll
    for (int mf = 0; mf < 2; ++mf) {
      const int ar = mf * 16 + lr;
      half8 a = *(const half8*)&sX[ar * NH + (koff ^ ((ar & 7) << 3))];
#pragma unroll
      for (int nf = 0; nf < 6; ++nf)
        acc2[mf][nf] = __builtin_amdgcn_mfma_f32_16x16x32_f16(a, bw2[nf], acc2[mf][nf], 0, 0, 0);
    }
#pragma unroll
    for (int nf = 0; nf < 6; ++nf) bw2[nf] = bw2n[nf];
  }

  // ---- Layer 3: gelu -> dot w3 -> reduce -> sigmoid ----
  float p[2][4] = {};
#pragma unroll
  for (int nf = 0; nf < 6; ++nf) {
    const int col = wv * 96 + nf * 16 + lr;
    const float bv = b2[col], wvv = w3[col];
#pragma unroll
    for (int mf = 0; mf < 2; ++mf)
#pragma unroll
      for (int r = 0; r < 4; ++r)
        p[mf][r] += gelu_fast(acc2[mf][nf][r] + bv) * wvv;
  }
#pragma unroll
  for (int mf = 0; mf < 2; ++mf)
#pragma unroll
    for (int r = 0; r < 4; ++r) {
      float v = p[mf][r];
      v += __shfl_xor(v, 1, 16);
      v += __shfl_xor(v, 2, 16);
      v += __shfl_xor(v, 4, 16);
      v += __shfl_xor(v, 8, 16);
      if (lr == 0) sP[wv][mf * 16 + lk4 * 4 + r] = v;
    }
  __syncthreads();
  if (tid < 32) {
    float s = b3[0];
#pragma unroll
    for (int w = 0; w < 8; ++w) s += sP[w][tid];
    out[row0 + tid] = 1.0f / (1.0f + expf(-s));
  }
#undef STAGE
}

// ---------------------------------------------------------------------------
extern "C" void kernel_launch(void* const* d_in, const int* in_sizes, int n_in,
                              void* d_out, int out_size, void* d_ws, size_t ws_size,
                              hipStream_t stream) {
  (void)in_sizes; (void)n_in; (void)out_size; (void)ws_size;
  const float* hidden = (const float*)d_in[0];
  const int*   sid    = (const int*)d_in[1];
  const float* w1     = (const float*)d_in[2];
  const float* b1     = (const float*)d_in[3];
  const float* w2     = (const float*)d_in[4];
  const float* b2     = (const float*)d_in[5];
  const float* w3     = (const float*)d_in[6];
  const float* b3     = (const float*)d_in[7];
  float* out = (float*)d_out;

  char* p = (char*)d_ws;
  const size_t actE = (size_t)NM * NH;
  _Float16* Ahi = (_Float16*)p; p += actE * 2;
  _Float16* Alo = (_Float16*)p; p += actE * 2;
  _Float16* W   = (_Float16*)p; p += (size_t)2 * NH * NH * 2;

  prep_w_kernel<<<2 * 96 * NH / 256, 256, 0, stream>>>(w1, w2, W);
  pool_kernel<<<dim3(16, NB), 192, 0, stream>>>(hidden, sid, Ahi, Alo);
  mlp_kernel<<<NM / 32, 512, 0, stream>>>(Ahi, Alo, W, b1, b2, w3, b3, out);
}

// Round 12
// 203.656 us; speedup vs baseline: 1.6355x; 1.0627x over previous
//
#include <hip/hip_runtime.h>
#include <stdint.h>

#define NB 64
#define NT 512
#define NH 768
#define NS 128
#define NM (NB*NS)   // 8192 rows

typedef _Float16 half8 __attribute__((ext_vector_type(8)));
typedef _Float16 half4 __attribute__((ext_vector_type(4)));
typedef __attribute__((ext_vector_type(4))) float f32x4;

// gelu(x) = x*Phi(x), Phi via Abramowitz-Stegun 7.1.26 erf (|eps|<=1.5e-7)
__device__ __forceinline__ float gelu_fast(float x) {
  float ax = fabsf(x) * 0.70710678118654752440f;
  float t  = __builtin_amdgcn_rcpf(1.0f + 0.3275911f * ax);
  float e  = __expf(-ax * ax);
  float poly = t * (0.254829592f + t * (-0.284496736f +
               t * (1.421413741f + t * (-1.453152027f + t * 1.061405429f))));
  float erfv = 1.0f - poly * e;
  float phi  = 0.5f * (1.0f + copysignf(erfv, x));
  return x * phi;
}

// ---------------------------------------------------------------------------
// Weight prep: w[k][n] f32 -> blocked f16 layout W[w][n>>4][k>>3][n&15][k&7].
// B-fragment load (16 n-rows x 8 k) = ONE 256B-contiguous block.
// ---------------------------------------------------------------------------
__global__ void prep_w_kernel(const float* __restrict__ w1, const float* __restrict__ w2,
                              _Float16* __restrict__ W) {
  int id = blockIdx.x * 256 + threadIdx.x;   // 2*96*768 total
  int n  = id % NH;
  int t  = id / NH;
  int kc = t % 96;
  int w  = t / 96;
  const float* src = w ? w2 : w1;
  int k0 = kc * 8;
  half8 h;
#pragma unroll
  for (int i = 0; i < 8; ++i)
    h[i] = (_Float16)src[(size_t)(k0 + i) * NH + n];
  const size_t off = ((((size_t)w * 48 + (n >> 4)) * 96 + kc) * 16 + (n & 15)) * 8;
  *(half8*)&W[off] = h;
}

// ---------------------------------------------------------------------------
// Fully fused: pool (segment-mean) + 3-layer MLP + sigmoid, one kernel.
// Block = (batch b, group of 32 segments). 512 threads (8 waves).
//  Phase P (waves 0-5): two 16-seg sub-groups, each a CONTIGUOUS token chunk;
//    D=8 register ring of f32x4 loads; accumulate into LDS sAcc[32][768] f32.
//  Convert: in-place f32 -> f16 hi/lo (reg-staged across a barrier).
//  L1: A-fragments straight from LDS (zero staging barriers), W1 blocked
//      global->VGPR 1-deep prefetch, f16x2 MFMA -> x1=gelu -> sX (swizzled).
//  L2: from sX, W2 prefetch, f16 MFMA.  L3: gelu -> dot w3 -> reduce -> out.
// LDS: sAcc 96K (reused as Ahi|Alo 48K+48K) + sX 48K + sid 2K = ~146.5 KB.
// ---------------------------------------------------------------------------
__global__ __launch_bounds__(512)
void fused_kernel(const float* __restrict__ hidden, const int* __restrict__ sid,
                  const _Float16* __restrict__ Wp,
                  const float* __restrict__ b1, const float* __restrict__ b2,
                  const float* __restrict__ w3, const float* __restrict__ b3,
                  float* __restrict__ out) {
  __shared__ float    sAcc[32 * NH];    // 96 KB; becomes Ahi|Alo (f16) after convert
  __shared__ _Float16 sX[32 * NH];      // 48 KB
  __shared__ int      s_sid[NT];        // 2 KB; reused as sP at the end
  __shared__ short    s_e0[NS + 1];

  const int tid  = threadIdx.x;
  const int lane = tid & 63;
  const int wv   = tid >> 6;            // 0..7
  const int lr   = lane & 15;
  const int lk4  = lane >> 4;           // 0..3
  const int b  = blockIdx.y;
  const int s0 = blockIdx.x * 32;       // this block's first segment

  // ---- sid load + boundary table ----
  s_sid[tid] = sid[b * NT + tid];       // NT == 512 == blockDim
  __syncthreads();
  {
    const int t = tid;
    const int cur  = s_sid[t];
    const int prev = t ? s_sid[t - 1] : -1;
    for (int s = prev + 1; s <= cur; ++s) s_e0[s] = (short)t;
    if (t == NT - 1)
      for (int s = cur + 1; s <= NS; ++s) s_e0[s] = (short)NT;
  }
  // zero sAcc: 24576 f32 / 512 thr = 12 f32x4 each
#pragma unroll
  for (int i = 0; i < 12; ++i)
    *(f32x4*)&sAcc[(i * 512 + tid) * 4] = (f32x4){0.f, 0.f, 0.f, 0.f};
  __syncthreads();

  // ---- Phase P: pool. waves 0-5 active; two independent 16-seg sub-groups ----
  if (tid < 384) {
    const int tg   = (tid >= 192) ? 1 : 0;
    const int col  = (tid - tg * 192) * 4;          // f32x4 column
    const int sg0  = s0 + tg * 16;
    const int t0 = s_e0[sg0], t1 = s_e0[sg0 + 16];
    const float* hb = hidden + (size_t)b * NT * NH + col;
    if (t1 > t0) {
      constexpr int D = 8;
      f32x4 buf[D];
#pragma unroll
      for (int j = 0; j < D; ++j) {
        int tj = t0 + j; if (tj >= t1) tj = t1 - 1;
        buf[j] = *(const f32x4*)(hb + (size_t)tj * NH);
      }
      f32x4 acc = {0.f, 0.f, 0.f, 0.f};
      int cur = s_sid[t0];
      int t = t0;
      for (; t + D <= t1; t += D) {
#pragma unroll
        for (int j = 0; j < D; ++j) {
          f32x4 v = buf[j];
          int tn = t + j + D; if (tn >= t1) tn = t1 - 1;
          buf[j] = *(const f32x4*)(hb + (size_t)tn * NH);
          const int s = s_sid[t + j];
          if (s != cur) {                            // group-uniform branch
            *(f32x4*)&sAcc[(cur - s0) * NH + col] = acc;
            acc = (f32x4){0.f, 0.f, 0.f, 0.f};
            cur = s;
          }
          acc += v;
        }
      }
#pragma unroll
      for (int j = 0; j < D; ++j) {
        if (t + j < t1) {
          f32x4 v = buf[j];
          const int s = s_sid[t + j];
          if (s != cur) {
            *(f32x4*)&sAcc[(cur - s0) * NH + col] = acc;
            acc = (f32x4){0.f, 0.f, 0.f, 0.f};
            cur = s;
          }
          acc += v;
        }
      }
      *(f32x4*)&sAcc[(cur - s0) * NH + col] = acc;
    }
  }
  __syncthreads();

  // ---- Convert: sAcc f32 [32][768] -> in-place Ahi|Alo f16 (swizzled) ----
  _Float16* Ah = (_Float16*)sAcc;            // [32][768] f16, XOR-swizzled
  _Float16* Al = Ah + 32 * NH;
  {
    const int r  = tid >> 4;                 // 0..31
    const int c0 = (tid & 15) * 48;          // 48 cols per thread
    f32x4 vv[12];
#pragma unroll
    for (int i = 0; i < 12; ++i)
      vv[i] = *(const f32x4*)&sAcc[r * NH + c0 + i * 4];
    const int cnt = s_e0[s0 + r + 1] - s_e0[s0 + r];
    const float inv = 1.0f / (float)(cnt > 0 ? cnt : 1);
    __syncthreads();                         // all reads done before any writes
    const int xr = (r & 7) << 3;
#pragma unroll
    for (int i = 0; i < 12; ++i) {
      half4 h, l;
#pragma unroll
      for (int j = 0; j < 4; ++j) {
        float x = vv[i][j] * inv;
        h[j] = (_Float16)x;
        l[j] = (_Float16)(x - (float)h[j]);
      }
      const int idx = r * NH + ((c0 + i * 4) ^ xr);  // xr hits bits 3-5 only
      *(half4*)&Ah[idx] = h;
      *(half4*)&Al[idx] = l;
    }
  }
  __syncthreads();

  const _Float16* W1 = Wp;
  const _Float16* W2 = Wp + (size_t)NH * NH;

  // ---- Layer 1: A from LDS, W1 global 1-deep prefetch, 24 k32-steps ----
  f32x4 acc1[2][6] = {};
  {
    half8 bw[6], bwn[6];
#pragma unroll
    for (int nf = 0; nf < 6; ++nf)
      bw[nf] = *(const half8*)(W1 + ((size_t)(wv * 6 + nf) * 96 + lk4) * 128 + lr * 8);
    for (int g = 0; g < 24; ++g) {
      if (g < 23) {
#pragma unroll
        for (int nf = 0; nf < 6; ++nf)
          bwn[nf] = *(const half8*)(W1 + ((size_t)(wv * 6 + nf) * 96 + (g + 1) * 4 + lk4) * 128 + lr * 8);
      }
      const int koff = g * 32 + lk4 * 8;
#pragma unroll
      for (int mf = 0; mf < 2; ++mf) {
        const int ar = mf * 16 + lr;
        const int ad = ar * NH + (koff ^ ((ar & 7) << 3));
        half8 ah = *(const half8*)&Ah[ad];
        half8 al = *(const half8*)&Al[ad];
#pragma unroll
        for (int nf = 0; nf < 6; ++nf) {
          acc1[mf][nf] = __builtin_amdgcn_mfma_f32_16x16x32_f16(ah, bw[nf], acc1[mf][nf], 0, 0, 0);
          acc1[mf][nf] = __builtin_amdgcn_mfma_f32_16x16x32_f16(al, bw[nf], acc1[mf][nf], 0, 0, 0);
        }
      }
#pragma unroll
      for (int nf = 0; nf < 6; ++nf) bw[nf] = bwn[nf];
    }
  }

  // layer-1 epilogue: x1 = gelu(acc1 + b1) -> sX (k-XOR swizzled per row)
#pragma unroll
  for (int nf = 0; nf < 6; ++nf) {
    const int col = wv * 96 + nf * 16 + lr;
    const float bv = b1[col];
#pragma unroll
    for (int mf = 0; mf < 2; ++mf)
#pragma unroll
      for (int r = 0; r < 4; ++r) {
        const int row = mf * 16 + lk4 * 4 + r;
        sX[row * NH + (col ^ ((row & 7) << 3))] = (_Float16)gelu_fast(acc1[mf][nf][r] + bv);
      }
  }
  __syncthreads();

  // ---- Layer 2: from sX, W2 1-deep prefetch ----
  f32x4 acc2[2][6] = {};
  {
    half8 bw[6], bwn[6];
#pragma unroll
    for (int nf = 0; nf < 6; ++nf)
      bw[nf] = *(const half8*)(W2 + ((size_t)(wv * 6 + nf) * 96 + lk4) * 128 + lr * 8);
    for (int g = 0; g < 24; ++g) {
      if (g < 23) {
#pragma unroll
        for (int nf = 0; nf < 6; ++nf)
          bwn[nf] = *(const half8*)(W2 + ((size_t)(wv * 6 + nf) * 96 + (g + 1) * 4 + lk4) * 128 + lr * 8);
      }
      const int koff = g * 32 + lk4 * 8;
#pragma unroll
      for (int mf = 0; mf < 2; ++mf) {
        const int ar = mf * 16 + lr;
        half8 a = *(const half8*)&sX[ar * NH + (koff ^ ((ar & 7) << 3))];
#pragma unroll
        for (int nf = 0; nf < 6; ++nf)
          acc2[mf][nf] = __builtin_amdgcn_mfma_f32_16x16x32_f16(a, bw[nf], acc2[mf][nf], 0, 0, 0);
      }
#pragma unroll
      for (int nf = 0; nf < 6; ++nf) bw[nf] = bwn[nf];
    }
  }

  // ---- Layer 3: gelu -> dot w3 -> reduce -> sigmoid ----
  float p[2][4] = {};
#pragma unroll
  for (int nf = 0; nf < 6; ++nf) {
    const int col = wv * 96 + nf * 16 + lr;
    const float bv = b2[col], wvv = w3[col];
#pragma unroll
    for (int mf = 0; mf < 2; ++mf)
#pragma unroll
      for (int r = 0; r < 4; ++r)
        p[mf][r] += gelu_fast(acc2[mf][nf][r] + bv) * wvv;
  }
  float (*sP)[32] = (float(*)[32])s_sid;     // s_sid dead; 1 KB alias
#pragma unroll
  for (int mf = 0; mf < 2; ++mf)
#pragma unroll
    for (int r = 0; r < 4; ++r) {
      float v = p[mf][r];
      v += __shfl_xor(v, 1, 16);
      v += __shfl_xor(v, 2, 16);
      v += __shfl_xor(v, 4, 16);
      v += __shfl_xor(v, 8, 16);
      if (lr == 0) sP[wv][mf * 16 + lk4 * 4 + r] = v;
    }
  __syncthreads();
  if (tid < 32) {
    float s = b3[0];
#pragma unroll
    for (int w = 0; w < 8; ++w) s += sP[w][tid];
    out[b * NS + s0 + tid] = 1.0f / (1.0f + expf(-s));
  }
}

// ---------------------------------------------------------------------------
extern "C" void kernel_launch(void* const* d_in, const int* in_sizes, int n_in,
                              void* d_out, int out_size, void* d_ws, size_t ws_size,
                              hipStream_t stream) {
  (void)in_sizes; (void)n_in; (void)out_size; (void)ws_size;
  const float* hidden = (const float*)d_in[0];
  const int*   sid    = (const int*)d_in[1];
  const float* w1     = (const float*)d_in[2];
  const float* b1     = (const float*)d_in[3];
  const float* w2     = (const float*)d_in[4];
  const float* b2     = (const float*)d_in[5];
  const float* w3     = (const float*)d_in[6];
  const float* b3     = (const float*)d_in[7];
  float* out = (float*)d_out;

  _Float16* W = (_Float16*)d_ws;   // 2.3 MB

  prep_w_kernel<<<2 * 96 * NH / 256, 256, 0, stream>>>(w1, w2, W);
  fused_kernel<<<dim3(4, NB), 512, 0, stream>>>(hidden, sid, W, b1, b2, w3, b3, out);
}